// Round 8
// baseline (552.195 us; speedup 1.0000x reference)
//
#include <hip/hip_runtime.h>
#include <hip/hip_bf16.h>

// Problem constants (from reference): E=1e6 events, 3 nodes, MEM=4, RAW=2, TIME=4.
// Strategy:
//  1) Stable sort events by timestamp: bucket sort on t*2^15 (atomic scatter of
//     FULL 16B records, features carried through) + per-bucket insertion-sort
//     fixup keyed on (t_bits, idx) == JAX stable argsort.
//     NBUCK=2^15 is the sweet spot: active scatter tail-set = 32768 lines = 2MB
//     -> L2-resident -> 64B lines fill (4 recs/line) before writeback (2^18 gave
//     66MB write amp; 4096+sortseg+ef-regather gave 137MB k_scan fetch).
//     (Cooperative grid.sync fusion measured 3x WORSE on MI355X: device-scope
//      barriers flush per-XCD L2s. Keep separate dispatches.)
//  2) Chunked-speculative scan (GRU memory is contractive): one 4-LANE QUAD per
//     32-event chunk, WARM=64. Lane q owns memory component k=q; 12x14/12x4
//     matvecs split 3-rows-per-lane; DPP quad_perm gathers with xor-permuted
//     weight columns; src/dst GRU accumulators paired into v2f32 (v_pk_fma_f32).

#define NBUCK 32768
#define CHUNK 32
#define WARM  64

typedef unsigned int uint;
typedef float f2 __attribute__((ext_vector_type(2)));

__device__ __forceinline__ int bucket_of(float t) {
    int b = (int)(t * 32768.0f);
    if (b < 0) b = 0;
    if (b > NBUCK - 1) b = NBUCK - 1;
    return b;
}

// ---------------- sort kernels ----------------

__global__ void k_count(const float* __restrict__ ts, uint* __restrict__ cnt, int E) {
    int i = blockIdx.x * blockDim.x + threadIdx.x;
    if (i < E) {
        atomicAdd(&cnt[bucket_of(ts[i])], 1u);
    }
}

// 32 blocks x 256 threads, one uint4 (4 counters) per thread -> sums[32]
__global__ void k_block_sums(const uint* __restrict__ cnt, uint* __restrict__ sums) {
    __shared__ uint sd[256];
    int b = blockIdx.x, tid = threadIdx.x;
    const uint4* p = ((const uint4*)cnt) + (size_t)b * 256 + tid;
    uint4 v = *p;
    uint s = v.x + v.y + v.z + v.w;
    sd[tid] = s;
    __syncthreads();
    for (int off = 128; off > 0; off >>= 1) {
        if (tid < off) sd[tid] += sd[tid + off];
        __syncthreads();
    }
    if (tid == 0) sums[b] = sd[0];
}

// Fused: every block redundantly scans the 32 block sums in LDS, then applies
// its intra-block exclusive scan to its 1024 counters.
__global__ void k_scan_apply(uint* __restrict__ cnt, const uint* __restrict__ sums) {
    __shared__ uint sd[256];
    __shared__ uint ss[256];
    int b = blockIdx.x, tid = threadIdx.x;
    uint4* p = ((uint4*)cnt) + (size_t)b * 256 + tid;
    uint4 v = *p;
    uint tsum = v.x + v.y + v.z + v.w;
    sd[tid] = tsum;
    ss[tid] = (tid < 32) ? sums[tid] : 0u;
    __syncthreads();
    for (int off = 1; off < 256; off <<= 1) {
        uint u = (tid >= off) ? sd[tid - off] : 0u;
        uint w = (tid >= off) ? ss[tid - off] : 0u;
        __syncthreads();
        sd[tid] += u;
        ss[tid] += w;
        __syncthreads();
    }
    uint blockbase = (b == 0) ? 0u : ss[b - 1];  // exclusive sum of previous blocks
    uint base = blockbase + sd[tid] - tsum;      // exclusive for this thread's 4 elems
    uint4 o;
    o.x = base;
    o.y = base + v.x;
    o.z = o.y + v.y;
    o.w = o.z + v.z;
    *p = o;
}

__global__ void k_scatter(const int* __restrict__ src, const int* __restrict__ dst,
                          const float* __restrict__ ts, const float* __restrict__ ef,
                          uint* __restrict__ cnt, uint4* __restrict__ rec, int E) {
    int i = blockIdx.x * blockDim.x + threadIdx.x;
    if (i >= E) return;
    float t = ts[i];
    int b = bucket_of(t);
    uint pos = atomicAdd(&cnt[b], 1u);
    float2 f = ((const float2*)ef)[i];
    uint code = ((uint)src[i]) | (((uint)dst[i]) << 2) | (((uint)i) << 4);
    rec[pos] = make_uint4(code, __float_as_uint(t),
                          __float_as_uint(f.x), __float_as_uint(f.y));
}

// After scatter, cnt[b] == inclusive prefix (start of bucket b+1). Sort each
// bucket's records by (t_bits asc, idx asc) => deterministic stable order.
__global__ void k_fixup(const uint* __restrict__ cnt, uint4* __restrict__ rec) {
    int b = blockIdx.x * blockDim.x + threadIdx.x;
    if (b >= NBUCK) return;
    uint beg = (b == 0) ? 0u : cnt[b - 1];
    uint end = cnt[b];
    if (end - beg < 2u) return;
    for (uint i = beg + 1; i < end; i++) {
        uint4 r = rec[i];
        uint ki = r.x >> 4;
        uint kt = r.y;  // positive float bits: monotonic as uint
        int j = (int)i - 1;
        while (j >= (int)beg) {
            uint4 q = rec[j];
            if (q.y > kt || (q.y == kt && (q.x >> 4) > ki)) {
                rec[j + 1] = q;
                j--;
            } else break;
        }
        rec[(uint)(j + 1)] = r;
    }
}

// ---------------- scan kernel ----------------

// quad_perm DPP: xor1 = [1,0,3,2] = 0xB1, xor2 = [2,3,0,1] = 0x4E,
// xor3 = [3,2,1,0] = 0x1B.  1-cycle VALU cross-lane, no LDS.
template <int CTRL>
__device__ __forceinline__ float qp(float x) {
    return __int_as_float(
        __builtin_amdgcn_mov_dpp(__float_as_int(x), CTRL, 0xF, 0xF, true));
}

__device__ __forceinline__ f2 fma2(f2 a, f2 b, f2 c) {
    return __builtin_elementwise_fma(a, b, c);
}
__device__ __forceinline__ f2 mk2(float a, float b) {
    f2 r; r.x = a; r.y = b; return r;
}
__device__ __forceinline__ f2 splat2(float a) {
    f2 r; r.x = a; r.y = a; return r;
}
__device__ __forceinline__ f2 sigm2(f2 x) {
    f2 t = -1.442695041f * x;
    f2 e = mk2(__builtin_amdgcn_exp2f(t.x), __builtin_amdgcn_exp2f(t.y));
    f2 o = 1.0f + e;
    return mk2(__builtin_amdgcn_rcpf(o.x), __builtin_amdgcn_rcpf(o.y));
}
__device__ __forceinline__ f2 tanh2(f2 x) {
    f2 t = 2.885390082f * x;
    f2 e = mk2(__builtin_amdgcn_exp2f(t.x), __builtin_amdgcn_exp2f(t.y));
    f2 o = 1.0f + e;
    f2 r = mk2(__builtin_amdgcn_rcpf(o.x), __builtin_amdgcn_rcpf(o.y));
    return fma2(splat2(-2.0f), r, splat2(1.0f));
}

__global__ void __launch_bounds__(256) k_scan(
    const uint4* __restrict__ rec,
    const float* __restrict__ Wlin, const float* __restrict__ blin,
    const float* __restrict__ Wtime, const float* __restrict__ btime,
    const float* __restrict__ Wih, const float* __restrict__ Whh,
    const float* __restrict__ bih, const float* __restrict__ bhh,
    float* __restrict__ out, int E, int nchunk) {
    // LDS weight cache: [0,168) Wih, [168,216) Whh, [216,228) bih, [228,240) bhh,
    // [240,260) Wlin, [260,262) blin, [262,266) w_t, [266,270) b_time
    __shared__ float sW[272];
    int tid = threadIdx.x;
    for (int i = tid; i < 270; i += 256) {
        float v;
        if (i < 168) v = Wih[i];
        else if (i < 216) v = Whh[i - 168];
        else if (i < 228) v = bih[i - 216];
        else if (i < 240) v = bhh[i - 228];
        else if (i < 260) v = Wlin[i - 240];
        else if (i < 262) v = blin[i - 260];
        else if (i < 266) v = Wtime[i - 262];
        else v = btime[i - 266];
        sW[i] = v;
    }
    __syncthreads();

    int g = blockIdx.x * 256 + tid;
    int c = g >> 2;           // one chain (chunk) per 4-lane quad
    if (c >= nchunk) return;
    int q = tid & 3;          // this lane owns memory component k=q

    // Per-lane weight preload as DUPLICATED f2 pairs (lo = src-GRU, hi = dst-GRU
    // share the same weight). Columns xor-permuted to match DPP gather order.
    f2 A2[3][4], B2[3][4], P2[3][4], H2[3][4], bh2[3];
    float Fw[3][2], bi[3];
#pragma unroll
    for (int gate = 0; gate < 3; gate++) {   // rows q, 4+q, 8+q  (r, z, n)
        int row = gate * 4 + q;
#pragma unroll
        for (int cc = 0; cc < 4; cc++) {
            int col = q ^ cc;
            A2[gate][cc] = splat2(sW[row * 14 + col]);        // x[0:4]  (own mem)
            B2[gate][cc] = splat2(sW[row * 14 + 4 + col]);    // x[4:8]  (other mem)
            P2[gate][cc] = splat2(sW[row * 14 + 10 + col]);   // x[10:14] (phi)
            H2[gate][cc] = splat2(sW[168 + row * 4 + col]);   // W_hh
        }
        Fw[gate][0] = sW[row * 14 + 8];
        Fw[gate][1] = sW[row * 14 + 9];
        bi[gate] = sW[216 + row];
        bh2[gate] = splat2(sW[228 + row]);
    }
    float wtq = sW[262 + q], btq = sW[266 + q];
    float wl0s = sW[240 + q], wl0d = sW[244 + q];
    float wl1s = sW[250 + q], wl1d = sW[254 + q];
    float wf00 = sW[248], wf01 = sW[249], wf10 = sW[258], wf11 = sW[259];
    float bl0 = sW[260], bl1 = sW[261];

    // own component of each node's memory; lu replicated across the quad
    float m0 = 0.f, m1 = 0.f, m2 = 0.f;
    float lu0 = 0.f, lu1 = 0.f, lu2 = 0.f;

    int emit0 = c * CHUNK;
    int j0 = emit0 - WARM;
    if (j0 < 0) j0 = 0;
    int jend = emit0 + CHUNK;
    if (jend > E) jend = E;

    uint4 r = rec[j0];  // all 4 lanes of the quad load the same address
    for (int j = j0; j < jend; j++) {
        int jn = (j + 1 < jend) ? j + 1 : j;
        uint4 rn = rec[jn];  // state-independent prefetch of next record

        uint code = r.x;
        float t = __uint_as_float(r.y);
        float f0 = __uint_as_float(r.z);
        float f1 = __uint_as_float(r.w);
        int s = (int)(code & 3u);
        int d = (int)((code >> 2) & 3u);
        uint oi = code >> 4;

        float sm = (s == 0) ? m0 : ((s == 1) ? m1 : m2);
        float dm = (d == 0) ? m0 : ((d == 1) ? m1 : m2);
        float lus = (s == 0) ? lu0 : ((s == 1) ? lu1 : lu2);
        float lud = (d == 0) ? lu0 : ((d == 1) ? lu1 : lu2);
        float ps = __cosf(fmaf(wtq, t - lus, btq));
        float pd = __cosf(fmaf(wtq, t - lud, btq));

        if (j >= emit0) {
            // distributed logit: own-component partials, butterfly quad-reduce
            float p0 = fmaf(wl0s, sm, wl0d * dm);
            float p1 = fmaf(wl1s, sm, wl1d * dm);
            p0 += qp<0xB1>(p0);
            p0 += qp<0x4E>(p0);
            p1 += qp<0xB1>(p1);
            p1 += qp<0x4E>(p1);
            if (q == 0) {
                float l0 = fmaf(wf01, f1, fmaf(wf00, f0, p0 + bl0));
                float l1 = fmaf(wf11, f1, fmaf(wf10, f0, p1 + bl1));
                ((float2*)out)[oi] = make_float2(l0, l1);
            }
        }

        // quad all-gather (xor order: element cc = component q^cc)
        float smg1 = qp<0xB1>(sm), smg2 = qp<0x4E>(sm), smg3 = qp<0x1B>(sm);
        float dmg1 = qp<0xB1>(dm), dmg2 = qp<0x4E>(dm), dmg3 = qp<0x1B>(dm);
        float psg1 = qp<0xB1>(ps), psg2 = qp<0x4E>(ps), psg3 = qp<0x1B>(ps);
        float pdg1 = qp<0xB1>(pd), pdg2 = qp<0x4E>(pd), pdg3 = qp<0x1B>(pd);

        // pairs: SD = (sm_c, dm_c)  (A-block & W_hh input),
        //        DS = (dm_c, sm_c)  (B-block input, swapped),
        //        PP = (ps_c, pd_c)  (phi block input)
        f2 SD[4] = {mk2(sm, dm), mk2(smg1, dmg1), mk2(smg2, dmg2), mk2(smg3, dmg3)};
        f2 DS[4] = {mk2(dm, sm), mk2(dmg1, smg1), mk2(dmg2, smg2), mk2(dmg3, smg3)};
        f2 PP[4] = {mk2(ps, pd), mk2(psg1, pdg1), mk2(psg2, pdg2), mk2(psg3, pdg3)};

        // 3 gate-rows per lane (rows q, 4+q, 8+q); lo half = src-GRU, hi = dst.
        f2 gx2[3], gh2[3];
#pragma unroll
        for (int gate = 0; gate < 3; gate++) {
            float base = fmaf(Fw[gate][0], f0, fmaf(Fw[gate][1], f1, bi[gate]));
            f2 acc = splat2(base);
            f2 hh = bh2[gate];
#pragma unroll
            for (int cc = 0; cc < 4; cc++) {
                acc = fma2(A2[gate][cc], SD[cc], acc);
                acc = fma2(B2[gate][cc], DS[cc], acc);
                acc = fma2(P2[gate][cc], PP[cc], acc);
                hh = fma2(H2[gate][cc], SD[cc], hh);
            }
            gx2[gate] = acc;
            gh2[gate] = hh;
        }

        f2 r2 = sigm2(gx2[0] + gh2[0]);
        f2 z2 = sigm2(gx2[1] + gh2[1]);
        f2 n2 = tanh2(fma2(r2, gh2[2], gx2[2]));
        f2 newm2 = fma2(z2, SD[0] - n2, n2);  // (1-z)*n + z*h, paired (src,dst)
        float newS = newm2.x;
        float newD = newm2.y;

        bool s0 = (s == 0), s1 = (s == 1), s2 = (s == 2);
        bool d0 = (d == 0), d1 = (d == 1), d2 = (d == 2);
        m0 = d0 ? newD : (s0 ? newS : m0);
        m1 = d1 ? newD : (s1 ? newS : m1);
        m2 = d2 ? newD : (s2 ? newS : m2);
        lu0 = (s0 || d0) ? t : lu0;
        lu1 = (s1 || d1) ? t : lu1;
        lu2 = (s2 || d2) ? t : lu2;

        r = rn;
    }
}

// ---------------- launcher ----------------

extern "C" void kernel_launch(void* const* d_in, const int* in_sizes, int n_in,
                              void* d_out, int out_size, void* d_ws, size_t ws_size,
                              hipStream_t stream) {
    const int* src = (const int*)d_in[0];
    const int* dst = (const int*)d_in[1];
    const float* ts = (const float*)d_in[2];
    const float* ef = (const float*)d_in[3];
    const float* Wlin = (const float*)d_in[4];
    const float* blin = (const float*)d_in[5];
    const float* Wtime = (const float*)d_in[6];
    const float* btime = (const float*)d_in[7];
    const float* Wih = (const float*)d_in[8];
    const float* Whh = (const float*)d_in[9];
    const float* bih = (const float*)d_in[10];
    const float* bhh = (const float*)d_in[11];
    float* out = (float*)d_out;
    int E = in_sizes[0];

    // workspace layout: rec[E] (16B each) | cnt[NBUCK] u32 | sums[32] u32
    unsigned char* ws = (unsigned char*)d_ws;
    uint4* rec = (uint4*)ws;
    size_t off = ((size_t)E * 16 + 255) & ~(size_t)255;
    uint* cnt = (uint*)(ws + off);
    uint* sums = (uint*)(ws + off + (size_t)NBUCK * 4);

    hipMemsetAsync(cnt, 0, (size_t)NBUCK * sizeof(uint), stream);

    int tb = 256;
    int gE = (E + tb - 1) / tb;
    k_count<<<gE, tb, 0, stream>>>(ts, cnt, E);
    k_block_sums<<<NBUCK / 1024, 256, 0, stream>>>(cnt, sums);
    k_scan_apply<<<NBUCK / 1024, 256, 0, stream>>>(cnt, sums);
    k_scatter<<<gE, tb, 0, stream>>>(src, dst, ts, ef, cnt, rec, E);
    k_fixup<<<NBUCK / 256, 256, 0, stream>>>(cnt, rec);

    int nchunk = (E + CHUNK - 1) / CHUNK;
    int nthreads = nchunk * 4;  // 4 lanes per chain
    int gS = (nthreads + 255) / 256;
    k_scan<<<gS, 256, 0, stream>>>(rec, Wlin, blin, Wtime, btime, Wih, Whh, bih, bhh,
                                   out, E, nchunk);
}

// Round 9
// 281.329 us; speedup vs baseline: 1.9628x; 1.9628x over previous
//
#include <hip/hip_runtime.h>
#include <hip/hip_bf16.h>

// Problem constants (from reference): E=1e6 events, 3 nodes, MEM=4, RAW=2, TIME=4.
// Strategy:
//  1) Stable sort events by timestamp: bucket sort on t*2^15 (atomic scatter of
//     FULL 16B records) + per-bucket WAVE-PARALLEL rank sort keyed on
//     (t_bits, idx) == JAX stable argsort.
//     NBUCK=2^15: scatter tail-set = 32768 lines = 2MB -> L2-resident -> full
//     64B lines written back once (2^18 gave 66MB write amp). lambda=30.5 per
//     bucket; fixup is ONE WAVE per bucket (serial-thread version measured
//     290us latency-bound): coalesced load -> keys in LDS -> per-lane O(n)
//     broadcast rank -> direct write to rec[beg+rank].
//     (Cooperative grid.sync fusion measured 3x WORSE on MI355X: device-scope
//      barriers flush per-XCD L2s. Keep separate dispatches.)
//  2) Chunked-speculative scan (GRU memory is contractive): one 4-LANE QUAD per
//     32-event chunk, WARM=64. Lane q owns memory component k=q; 12x14/12x4
//     matvecs split 3-rows-per-lane; DPP quad_perm gathers with xor-permuted
//     weight columns; src/dst GRU accumulators paired into v2f32 (v_pk_fma_f32).

#define NBUCK 32768
#define CHUNK 32
#define WARM  64
#define FIXW  4      // waves (buckets) per fixup block
#define SEGCAP 256   // max bucket size handled in LDS (lambda=30.5 -> P(n>256)~0)

typedef unsigned int uint;
typedef unsigned long long ull;
typedef float f2 __attribute__((ext_vector_type(2)));

__device__ __forceinline__ int bucket_of(float t) {
    int b = (int)(t * 32768.0f);
    if (b < 0) b = 0;
    if (b > NBUCK - 1) b = NBUCK - 1;
    return b;
}

// ---------------- sort kernels ----------------

__global__ void k_count(const float* __restrict__ ts, uint* __restrict__ cnt, int E) {
    int i = blockIdx.x * blockDim.x + threadIdx.x;
    if (i < E) {
        atomicAdd(&cnt[bucket_of(ts[i])], 1u);
    }
}

// 32 blocks x 256 threads, one uint4 (4 counters) per thread -> sums[32]
__global__ void k_block_sums(const uint* __restrict__ cnt, uint* __restrict__ sums) {
    __shared__ uint sd[256];
    int b = blockIdx.x, tid = threadIdx.x;
    const uint4* p = ((const uint4*)cnt) + (size_t)b * 256 + tid;
    uint4 v = *p;
    uint s = v.x + v.y + v.z + v.w;
    sd[tid] = s;
    __syncthreads();
    for (int off = 128; off > 0; off >>= 1) {
        if (tid < off) sd[tid] += sd[tid + off];
        __syncthreads();
    }
    if (tid == 0) sums[b] = sd[0];
}

// Fused: every block redundantly scans the 32 block sums in LDS, then applies
// its intra-block exclusive scan to its 1024 counters.
__global__ void k_scan_apply(uint* __restrict__ cnt, const uint* __restrict__ sums) {
    __shared__ uint sd[256];
    __shared__ uint ss[256];
    int b = blockIdx.x, tid = threadIdx.x;
    uint4* p = ((uint4*)cnt) + (size_t)b * 256 + tid;
    uint4 v = *p;
    uint tsum = v.x + v.y + v.z + v.w;
    sd[tid] = tsum;
    ss[tid] = (tid < 32) ? sums[tid] : 0u;
    __syncthreads();
    for (int off = 1; off < 256; off <<= 1) {
        uint u = (tid >= off) ? sd[tid - off] : 0u;
        uint w = (tid >= off) ? ss[tid - off] : 0u;
        __syncthreads();
        sd[tid] += u;
        ss[tid] += w;
        __syncthreads();
    }
    uint blockbase = (b == 0) ? 0u : ss[b - 1];  // exclusive sum of previous blocks
    uint base = blockbase + sd[tid] - tsum;      // exclusive for this thread's 4 elems
    uint4 o;
    o.x = base;
    o.y = base + v.x;
    o.z = o.y + v.y;
    o.w = o.z + v.z;
    *p = o;
}

__global__ void k_scatter(const int* __restrict__ src, const int* __restrict__ dst,
                          const float* __restrict__ ts, const float* __restrict__ ef,
                          uint* __restrict__ cnt, uint4* __restrict__ rec, int E) {
    int i = blockIdx.x * blockDim.x + threadIdx.x;
    if (i >= E) return;
    float t = ts[i];
    int b = bucket_of(t);
    uint pos = atomicAdd(&cnt[b], 1u);
    float2 f = ((const float2*)ef)[i];
    uint code = ((uint)src[i]) | (((uint)dst[i]) << 2) | (((uint)i) << 4);
    rec[pos] = make_uint4(code, __float_as_uint(t),
                          __float_as_uint(f.x), __float_as_uint(f.y));
}

// After scatter, cnt[b] == inclusive prefix (start of bucket b+1). One WAVE per
// bucket: stable rank sort by key64 = (t_bits<<32) | idx (unique per event).
__global__ void __launch_bounds__(256) k_fixup(const uint* __restrict__ cnt,
                                               uint4* __restrict__ rec) {
    __shared__ ull sk[FIXW][SEGCAP];
    int wave = threadIdx.x >> 6;
    int lane = threadIdx.x & 63;
    int b = blockIdx.x * FIXW + wave;
    bool active = (b < NBUCK);
    uint beg = 0u, end = 0u, n = 0u;
    if (active) {
        beg = (b == 0) ? 0u : cnt[b - 1];
        end = cnt[b];
        n = end - beg;
    }
    bool small = active && (n >= 2u) && (n <= SEGCAP);

    uint4 myrec[SEGCAP / 64];
    int nch = small ? (int)((n + 63u) >> 6) : 0;
    for (int c = 0; c < nch; c++) {
        uint i = (uint)(c * 64 + lane);
        if (i < n) {
            uint4 r = rec[beg + i];   // coalesced: contiguous 16B records
            myrec[c] = r;
            sk[wave][i] = ((ull)r.y << 32) | (ull)(r.x >> 4);
        }
    }
    __syncthreads();  // all threads reach this (no early returns)
    for (int c = 0; c < nch; c++) {
        uint i = (uint)(c * 64 + lane);
        if (i < n) {
            ull k = sk[wave][i];
            uint rk = 0;
            for (uint j = 0; j < n; j++) {   // broadcast LDS read, conflict-free
                rk += (sk[wave][j] < k) ? 1u : 0u;
            }
            rec[beg + rk] = myrec[c];        // unique keys -> bijective ranks
        }
    }
    // statistically-impossible overflow: serial insertion by lane 0
    if (active && (n > SEGCAP) && lane == 0) {
        for (uint i = beg + 1; i < end; i++) {
            uint4 r = rec[i];
            ull kk = ((ull)r.y << 32) | (ull)(r.x >> 4);
            int j = (int)i - 1;
            while (j >= (int)beg) {
                uint4 qq = rec[j];
                ull kq = ((ull)qq.y << 32) | (ull)(qq.x >> 4);
                if (kq > kk) { rec[j + 1] = qq; j--; } else break;
            }
            rec[(uint)(j + 1)] = r;
        }
    }
}

// ---------------- scan kernel ----------------

// quad_perm DPP: xor1 = [1,0,3,2] = 0xB1, xor2 = [2,3,0,1] = 0x4E,
// xor3 = [3,2,1,0] = 0x1B.  1-cycle VALU cross-lane, no LDS.
template <int CTRL>
__device__ __forceinline__ float qp(float x) {
    return __int_as_float(
        __builtin_amdgcn_mov_dpp(__float_as_int(x), CTRL, 0xF, 0xF, true));
}

__device__ __forceinline__ f2 fma2(f2 a, f2 b, f2 c) {
    return __builtin_elementwise_fma(a, b, c);
}
__device__ __forceinline__ f2 mk2(float a, float b) {
    f2 r; r.x = a; r.y = b; return r;
}
__device__ __forceinline__ f2 splat2(float a) {
    f2 r; r.x = a; r.y = a; return r;
}
__device__ __forceinline__ f2 sigm2(f2 x) {
    f2 t = -1.442695041f * x;
    f2 e = mk2(__builtin_amdgcn_exp2f(t.x), __builtin_amdgcn_exp2f(t.y));
    f2 o = 1.0f + e;
    return mk2(__builtin_amdgcn_rcpf(o.x), __builtin_amdgcn_rcpf(o.y));
}
__device__ __forceinline__ f2 tanh2(f2 x) {
    f2 t = 2.885390082f * x;
    f2 e = mk2(__builtin_amdgcn_exp2f(t.x), __builtin_amdgcn_exp2f(t.y));
    f2 o = 1.0f + e;
    f2 r = mk2(__builtin_amdgcn_rcpf(o.x), __builtin_amdgcn_rcpf(o.y));
    return fma2(splat2(-2.0f), r, splat2(1.0f));
}

__global__ void __launch_bounds__(256) k_scan(
    const uint4* __restrict__ rec,
    const float* __restrict__ Wlin, const float* __restrict__ blin,
    const float* __restrict__ Wtime, const float* __restrict__ btime,
    const float* __restrict__ Wih, const float* __restrict__ Whh,
    const float* __restrict__ bih, const float* __restrict__ bhh,
    float* __restrict__ out, int E, int nchunk) {
    // LDS weight cache: [0,168) Wih, [168,216) Whh, [216,228) bih, [228,240) bhh,
    // [240,260) Wlin, [260,262) blin, [262,266) w_t, [266,270) b_time
    __shared__ float sW[272];
    int tid = threadIdx.x;
    for (int i = tid; i < 270; i += 256) {
        float v;
        if (i < 168) v = Wih[i];
        else if (i < 216) v = Whh[i - 168];
        else if (i < 228) v = bih[i - 216];
        else if (i < 240) v = bhh[i - 228];
        else if (i < 260) v = Wlin[i - 240];
        else if (i < 262) v = blin[i - 260];
        else if (i < 266) v = Wtime[i - 262];
        else v = btime[i - 266];
        sW[i] = v;
    }
    __syncthreads();

    int g = blockIdx.x * 256 + tid;
    int c = g >> 2;           // one chain (chunk) per 4-lane quad
    if (c >= nchunk) return;
    int q = tid & 3;          // this lane owns memory component k=q

    // Per-lane weight preload as DUPLICATED f2 pairs (lo = src-GRU, hi = dst-GRU
    // share the same weight). Columns xor-permuted to match DPP gather order.
    f2 A2[3][4], B2[3][4], P2[3][4], H2[3][4], bh2[3];
    float Fw[3][2], bi[3];
#pragma unroll
    for (int gate = 0; gate < 3; gate++) {   // rows q, 4+q, 8+q  (r, z, n)
        int row = gate * 4 + q;
#pragma unroll
        for (int cc = 0; cc < 4; cc++) {
            int col = q ^ cc;
            A2[gate][cc] = splat2(sW[row * 14 + col]);        // x[0:4]  (own mem)
            B2[gate][cc] = splat2(sW[row * 14 + 4 + col]);    // x[4:8]  (other mem)
            P2[gate][cc] = splat2(sW[row * 14 + 10 + col]);   // x[10:14] (phi)
            H2[gate][cc] = splat2(sW[168 + row * 4 + col]);   // W_hh
        }
        Fw[gate][0] = sW[row * 14 + 8];
        Fw[gate][1] = sW[row * 14 + 9];
        bi[gate] = sW[216 + row];
        bh2[gate] = splat2(sW[228 + row]);
    }
    float wtq = sW[262 + q], btq = sW[266 + q];
    float wl0s = sW[240 + q], wl0d = sW[244 + q];
    float wl1s = sW[250 + q], wl1d = sW[254 + q];
    float wf00 = sW[248], wf01 = sW[249], wf10 = sW[258], wf11 = sW[259];
    float bl0 = sW[260], bl1 = sW[261];

    // own component of each node's memory; lu replicated across the quad
    float m0 = 0.f, m1 = 0.f, m2 = 0.f;
    float lu0 = 0.f, lu1 = 0.f, lu2 = 0.f;

    int emit0 = c * CHUNK;
    int j0 = emit0 - WARM;
    if (j0 < 0) j0 = 0;
    int jend = emit0 + CHUNK;
    if (jend > E) jend = E;

    uint4 r = rec[j0];  // all 4 lanes of the quad load the same address
    for (int j = j0; j < jend; j++) {
        int jn = (j + 1 < jend) ? j + 1 : j;
        uint4 rn = rec[jn];  // state-independent prefetch of next record

        uint code = r.x;
        float t = __uint_as_float(r.y);
        float f0 = __uint_as_float(r.z);
        float f1 = __uint_as_float(r.w);
        int s = (int)(code & 3u);
        int d = (int)((code >> 2) & 3u);
        uint oi = code >> 4;

        float sm = (s == 0) ? m0 : ((s == 1) ? m1 : m2);
        float dm = (d == 0) ? m0 : ((d == 1) ? m1 : m2);
        float lus = (s == 0) ? lu0 : ((s == 1) ? lu1 : lu2);
        float lud = (d == 0) ? lu0 : ((d == 1) ? lu1 : lu2);
        float ps = __cosf(fmaf(wtq, t - lus, btq));
        float pd = __cosf(fmaf(wtq, t - lud, btq));

        if (j >= emit0) {
            // distributed logit: own-component partials, butterfly quad-reduce
            float p0 = fmaf(wl0s, sm, wl0d * dm);
            float p1 = fmaf(wl1s, sm, wl1d * dm);
            p0 += qp<0xB1>(p0);
            p0 += qp<0x4E>(p0);
            p1 += qp<0xB1>(p1);
            p1 += qp<0x4E>(p1);
            if (q == 0) {
                float l0 = fmaf(wf01, f1, fmaf(wf00, f0, p0 + bl0));
                float l1 = fmaf(wf11, f1, fmaf(wf10, f0, p1 + bl1));
                ((float2*)out)[oi] = make_float2(l0, l1);
            }
        }

        // quad all-gather (xor order: element cc = component q^cc)
        float smg1 = qp<0xB1>(sm), smg2 = qp<0x4E>(sm), smg3 = qp<0x1B>(sm);
        float dmg1 = qp<0xB1>(dm), dmg2 = qp<0x4E>(dm), dmg3 = qp<0x1B>(dm);
        float psg1 = qp<0xB1>(ps), psg2 = qp<0x4E>(ps), psg3 = qp<0x1B>(ps);
        float pdg1 = qp<0xB1>(pd), pdg2 = qp<0x4E>(pd), pdg3 = qp<0x1B>(pd);

        // pairs: SD = (sm_c, dm_c)  (A-block & W_hh input),
        //        DS = (dm_c, sm_c)  (B-block input, swapped),
        //        PP = (ps_c, pd_c)  (phi block input)
        f2 SD[4] = {mk2(sm, dm), mk2(smg1, dmg1), mk2(smg2, dmg2), mk2(smg3, dmg3)};
        f2 DS[4] = {mk2(dm, sm), mk2(dmg1, smg1), mk2(dmg2, smg2), mk2(dmg3, smg3)};
        f2 PP[4] = {mk2(ps, pd), mk2(psg1, pdg1), mk2(psg2, pdg2), mk2(psg3, pdg3)};

        // 3 gate-rows per lane (rows q, 4+q, 8+q); lo half = src-GRU, hi = dst.
        f2 gx2[3], gh2[3];
#pragma unroll
        for (int gate = 0; gate < 3; gate++) {
            float base = fmaf(Fw[gate][0], f0, fmaf(Fw[gate][1], f1, bi[gate]));
            f2 acc = splat2(base);
            f2 hh = bh2[gate];
#pragma unroll
            for (int cc = 0; cc < 4; cc++) {
                acc = fma2(A2[gate][cc], SD[cc], acc);
                acc = fma2(B2[gate][cc], DS[cc], acc);
                acc = fma2(P2[gate][cc], PP[cc], acc);
                hh = fma2(H2[gate][cc], SD[cc], hh);
            }
            gx2[gate] = acc;
            gh2[gate] = hh;
        }

        f2 r2 = sigm2(gx2[0] + gh2[0]);
        f2 z2 = sigm2(gx2[1] + gh2[1]);
        f2 n2 = tanh2(fma2(r2, gh2[2], gx2[2]));
        f2 newm2 = fma2(z2, SD[0] - n2, n2);  // (1-z)*n + z*h, paired (src,dst)
        float newS = newm2.x;
        float newD = newm2.y;

        bool s0 = (s == 0), s1 = (s == 1), s2 = (s == 2);
        bool d0 = (d == 0), d1 = (d == 1), d2 = (d == 2);
        m0 = d0 ? newD : (s0 ? newS : m0);
        m1 = d1 ? newD : (s1 ? newS : m1);
        m2 = d2 ? newD : (s2 ? newS : m2);
        lu0 = (s0 || d0) ? t : lu0;
        lu1 = (s1 || d1) ? t : lu1;
        lu2 = (s2 || d2) ? t : lu2;

        r = rn;
    }
}

// ---------------- launcher ----------------

extern "C" void kernel_launch(void* const* d_in, const int* in_sizes, int n_in,
                              void* d_out, int out_size, void* d_ws, size_t ws_size,
                              hipStream_t stream) {
    const int* src = (const int*)d_in[0];
    const int* dst = (const int*)d_in[1];
    const float* ts = (const float*)d_in[2];
    const float* ef = (const float*)d_in[3];
    const float* Wlin = (const float*)d_in[4];
    const float* blin = (const float*)d_in[5];
    const float* Wtime = (const float*)d_in[6];
    const float* btime = (const float*)d_in[7];
    const float* Wih = (const float*)d_in[8];
    const float* Whh = (const float*)d_in[9];
    const float* bih = (const float*)d_in[10];
    const float* bhh = (const float*)d_in[11];
    float* out = (float*)d_out;
    int E = in_sizes[0];

    // workspace layout: rec[E] (16B each) | cnt[NBUCK] u32 | sums[32] u32
    unsigned char* ws = (unsigned char*)d_ws;
    uint4* rec = (uint4*)ws;
    size_t off = ((size_t)E * 16 + 255) & ~(size_t)255;
    uint* cnt = (uint*)(ws + off);
    uint* sums = (uint*)(ws + off + (size_t)NBUCK * 4);

    hipMemsetAsync(cnt, 0, (size_t)NBUCK * sizeof(uint), stream);

    int tb = 256;
    int gE = (E + tb - 1) / tb;
    k_count<<<gE, tb, 0, stream>>>(ts, cnt, E);
    k_block_sums<<<NBUCK / 1024, 256, 0, stream>>>(cnt, sums);
    k_scan_apply<<<NBUCK / 1024, 256, 0, stream>>>(cnt, sums);
    k_scatter<<<gE, tb, 0, stream>>>(src, dst, ts, ef, cnt, rec, E);
    k_fixup<<<(NBUCK + FIXW - 1) / FIXW, 256, 0, stream>>>(cnt, rec);

    int nchunk = (E + CHUNK - 1) / CHUNK;
    int nthreads = nchunk * 4;  // 4 lanes per chain
    int gS = (nthreads + 255) / 256;
    k_scan<<<gS, 256, 0, stream>>>(rec, Wlin, blin, Wtime, btime, Wih, Whh, bih, bhh,
                                   out, E, nchunk);
}